// Round 5
// baseline (199.166 us; speedup 1.0000x reference)
//
#include <hip/hip_runtime.h>
#include <hip/hip_bf16.h>

#define BDIM 16384
#define CDIM 128
#define FDIM 5000
#define EDIM 20000
#define ELLW 16
#define MAXOVF 20000
#define NT4  10       // n-tile QUADS: 40 n-tiles / 4

typedef __attribute__((ext_vector_type(8))) short short8;
typedef __attribute__((ext_vector_type(4))) float f32x4;
typedef __attribute__((ext_vector_type(2))) float f32x2;
typedef __attribute__((ext_vector_type(2))) int i32x2;
typedef __attribute__((ext_vector_type(8))) unsigned short upk8;
typedef __attribute__((ext_vector_type(4))) unsigned short upk4;
typedef __attribute__((ext_vector_type(2))) unsigned int u32x2;

__device__ __forceinline__ unsigned short f2bf(float f) {
    unsigned int u = __builtin_bit_cast(unsigned int, f);
    u = (u + 0x7fffu + ((u >> 16) & 1u)) >> 16;   // RNE
    return (unsigned short)u;
}
__device__ __forceinline__ float bf2f(unsigned short s) {
    unsigned int u = ((unsigned int)s) << 16;
    return __builtin_bit_cast(float, u);
}
__device__ __forceinline__ upk8 umax8(upk8 a, upk8 b) {
#if __has_builtin(__builtin_elementwise_max)
    return __builtin_elementwise_max(a, b);   // 4x v_pk_max_u16
#else
    upk8 r;
    #pragma unroll
    for (int j = 0; j < 8; ++j) r[j] = a[j] > b[j] ? a[j] : b[j];
    return r;
#endif
}
// single v_rcp_f32 (no -ffast-math in harness -> 1.0f/x emits the IEEE
// div sequence). VERIFIED WIN round 2: 178.96 -> 159.24 us.
__device__ __forceinline__ float fast_rcp(float x) {
#if __has_builtin(__builtin_amdgcn_rcpf)
    return __builtin_amdgcn_rcpf(x);
#else
    return 1.0f / x;
#endif
}
// order-preserving u16 key of a bf16 pattern h (per 16-bit half, packed u32):
// pos: k = h | 0x8000 ; neg: k = ~h  -> unsigned order == float order
// VERIFIED WIN round 4: 159.24 -> 153.83 us, absmax 0.0059 -> 0.0039.
__device__ __forceinline__ unsigned int key2(unsigned int h) {
    unsigned int t = (h >> 15) & 0x00010001u;
    return h ^ (t * 0x7FFFu + 0x80008000u);
}
// inverse: k -> bf16 bits
__device__ __forceinline__ unsigned short unkey(unsigned short k) {
    unsigned int s = (k >> 15) & 1u;
    return (unsigned short)(k ^ (0x8000u + ((s ^ 1u) * 0x7FFFu)));
}
// async global->LDS, 16B per lane; LDS dest = firstlane base + lane*16
__device__ __forceinline__ void gll16(const unsigned short* g, unsigned short* l) {
    __builtin_amdgcn_global_load_lds(
        (const __attribute__((address_space(1))) void*)g,
        (__attribute__((address_space(3))) void*)l, 16, 0, 0);
}

// ---------------------------------------------------------------------------
// prep1: blocks [0,1024): x f32 -> bf16 (2048 elems/block)
//        blocks [1024,1181): W[k][f] -> Wt[f][k] bf16, LDS-tiled
//        blocks [1181,1201): ELL init (all 16 slots = self), cur=1, ovf=0
// ---------------------------------------------------------------------------
__global__ __launch_bounds__(256) void prep1_kernel(
    const float* __restrict__ x, const float* __restrict__ W,
    unsigned short* __restrict__ xb, unsigned short* __restrict__ wt,
    unsigned short* __restrict__ ell, int* __restrict__ cur,
    int* __restrict__ ovf_cnt)
{
    __shared__ float lt[128][33];
    int bid = blockIdx.x, tid = threadIdx.x;
    if (bid < 1024) {
        size_t base = (size_t)bid * 2048 + (size_t)tid * 8;
        const f32x4* p = (const f32x4*)(x + base);
        f32x4 v0 = p[0], v1 = p[1];
        short8 o;
        o[0] = (short)f2bf(v0[0]); o[1] = (short)f2bf(v0[1]);
        o[2] = (short)f2bf(v0[2]); o[3] = (short)f2bf(v0[3]);
        o[4] = (short)f2bf(v1[0]); o[5] = (short)f2bf(v1[1]);
        o[6] = (short)f2bf(v1[2]); o[7] = (short)f2bf(v1[3]);
        *(short8*)(xb + base) = o;
    } else if (bid < 1181) {
        int f0 = (bid - 1024) * 32;
        int f_l = tid & 31, k0 = (tid >> 5) * 16;
        #pragma unroll
        for (int i = 0; i < 16; ++i) {
            int f = f0 + f_l;
            lt[k0 + i][f_l] = (f < FDIM) ? W[(size_t)(k0 + i) * FDIM + f] : 0.f;
        }
        __syncthreads();
        int f_l2 = tid >> 3, ks = (tid & 7) * 16;
        int f = f0 + f_l2;
        if (f < FDIM) {
            short8 o0, o1;
            #pragma unroll
            for (int j = 0; j < 8; ++j) o0[j] = (short)f2bf(lt[ks + j][f_l2]);
            #pragma unroll
            for (int j = 0; j < 8; ++j) o1[j] = (short)f2bf(lt[ks + 8 + j][f_l2]);
            *(short8*)(wt + (size_t)f * 128 + ks)     = o0;
            *(short8*)(wt + (size_t)f * 128 + ks + 8) = o1;
        }
    } else {
        int p = (bid - 1181) * 256 + tid;
        if (p < FDIM) {
            upk8 s;
            #pragma unroll
            for (int j = 0; j < 8; ++j) s[j] = (unsigned short)p;
            *(upk8*)(ell + (size_t)p * ELLW)     = s;
            *(upk8*)(ell + (size_t)p * ELLW + 8) = s;
            cur[p] = 1;
        }
        if (p == FDIM) *ovf_cnt = 0;
    }
}

// ---------------------------------------------------------------------------
// prep2: scatter children into ELL slots 1.. (order irrelevant: max).
// ---------------------------------------------------------------------------
__global__ __launch_bounds__(256) void prep2_kernel(
    const int* __restrict__ epar, const int* __restrict__ echild,
    int* __restrict__ cur, unsigned short* __restrict__ ell,
    int* __restrict__ ovf_cnt, int* __restrict__ ovf_pairs)
{
    int i = blockIdx.x * 256 + threadIdx.x;
    if (i < EDIM) {
        int p = epar[i], c = echild[i];
        if (p != c) {
            int pos = atomicAdd(&cur[p], 1);
            if (pos < ELLW) {
                ell[(size_t)p * ELLW + pos] = (unsigned short)c;
            } else {
                int j = atomicAdd(ovf_cnt, 1);
                if (j < MAXOVF) { ovf_pairs[2 * j] = p; ovf_pairs[2 * j + 1] = c; }
            }
        }
    }
}

// ---------------------------------------------------------------------------
// gemm8k2: = verified gemm8k (r4), with ONE change: the A fragments
// (af[16], 64 VGPR) are read from lA ONCE after the first barrier instead
// of re-read every n-tile. A-tile is invariant across the 4 tiles; this
// halves the wave's ds_read_b128 count (96 -> 48) in an LDS-read-bound
// kernel. VGPR budget at (512,4)=128 cap: af 64 + acc 32 + bf 8 + temps
// ~ 120 -> fits (r4's lighter no-sigmoid epilogue makes this viable).
// ---------------------------------------------------------------------------
__global__ __launch_bounds__(512, 4) void gemm8k2_kernel(
    const unsigned short* __restrict__ xb,   // [BDIM][128] bf16
    const unsigned short* __restrict__ wt,   // [FDIM][128] bf16
    const float* __restrict__ bias,
    unsigned short* __restrict__ probs16)    // [BDIM/8][FDIM][8] u16 keys
{
    __shared__ unsigned short lA[128 * 128];
    __shared__ unsigned short lB[128 * 128];

    int bid0 = blockIdx.x;
    int bid  = (bid0 & 7) * (128 * NT4 / 8) + (bid0 >> 3);   // XCD swizzle
    int bm = bid / NT4, bq = bid % NT4;
    int tid = threadIdx.x;
    int lane = tid & 63, w = tid >> 6;       // 8 waves
    int wm = w >> 2, wn = w & 3;
    int g = lane >> 4, lr = lane & 15;
    int lrow = lane >> 4;                    // row within 4-row chunk
    int lcol = (lane & 15) << 4;             // byte col

    auto stageA = [&]() {
        #pragma unroll
        for (int it = 0; it < 4; ++it) {
            int ci = w * 4 + it;             // chunk 0..31
            int row = ci * 4 + lrow;
            int sw = lcol ^ ((row & 7) << 4);
            gll16(xb + ((size_t)(bm * 128 + row) << 7) + (sw >> 1),
                  lA + ci * 512);
        }
    };
    auto stageB = [&](int bn) {
        #pragma unroll
        for (int it = 0; it < 4; ++it) {
            int ci = w * 4 + it;
            int row = ci * 4 + lrow;
            int sw = lcol ^ ((row & 7) << 4);
            gll16(wt + ((size_t)(bn * 128 + row) << 7) + (sw >> 1),
                  lB + ci * 512);
        }
    };
    auto epilogue = [&](int bn, f32x4 (&acc)[4][2]) {
        #pragma unroll
        for (int nj = 0; nj < 2; ++nj) {
            int f = bn * 128 + wn * 32 + nj * 16 + lr;
            bool ok = (f < FDIM);
            float bb = ok ? bias[f] : 0.f;
            #pragma unroll
            for (int mi = 0; mi < 4; ++mi) {
                float z0 = acc[mi][nj][0] + bb;
                float z1 = acc[mi][nj][1] + bb;
                float z2 = acc[mi][nj][2] + bb;
                float z3 = acc[mi][nj][3] + bb;
                unsigned int h01, h23;   // packed bf16 (low = first operand)
                asm("v_cvt_pk_bf16_f32 %0, %1, %2" : "=v"(h01) : "v"(z0), "v"(z1));
                asm("v_cvt_pk_bf16_f32 %0, %1, %2" : "=v"(h23) : "v"(z2), "v"(z3));
                u32x2 st;
                st[0] = key2(h01);
                st[1] = key2(h23);
                if (ok) {
                    int slab = bm * 16 + wm * 8 + mi * 2 + (g >> 1);
                    *(u32x2*)(probs16 + ((size_t)slab * FDIM + f) * 8 + (g & 1) * 4) = st;
                }
            }
        }
    };

    stageA();
    stageB(bq * 4);
    __syncthreads();                     // drains vmcnt -> tiles resident

    // A fragments hoisted: read ONCE, reused for all 4 n-tiles.
    short8 af[4][4];                     // [ks][mi], 64 VGPR
    #pragma unroll
    for (int ks = 0; ks < 4; ++ks) {
        int cbk = ks * 64 + g * 16;
        #pragma unroll
        for (int mi = 0; mi < 4; ++mi) {
            int row = wm * 64 + mi * 16 + lr;
            af[ks][mi] = *(const short8*)((const char*)lA + row * 256 + (cbk ^ ((row & 7) << 4)));
        }
    }

    f32x4 zero = {0.f, 0.f, 0.f, 0.f};
    for (int t = 0; t < 4; ++t) {
        f32x4 acc[4][2];
        #pragma unroll
        for (int mi = 0; mi < 4; ++mi) { acc[mi][0] = zero; acc[mi][1] = zero; }

        #pragma unroll
        for (int ks = 0; ks < 4; ++ks) {
            int cbk = ks * 64 + g * 16;
            short8 bf[2];
            #pragma unroll
            for (int nj = 0; nj < 2; ++nj) {
                int row = wn * 32 + nj * 16 + lr;
                bf[nj] = *(const short8*)((const char*)lB + row * 256 + (cbk ^ ((row & 7) << 4)));
            }
            #pragma unroll
            for (int mi = 0; mi < 4; ++mi)
                #pragma unroll
                for (int nj = 0; nj < 2; ++nj)
                    acc[mi][nj] = __builtin_amdgcn_mfma_f32_16x16x32_bf16(
                        af[ks][mi], bf[nj], acc[mi][nj], 0, 0, 0);
        }

        if (t < 3) {
            __syncthreads();             // all waves done reading lB(t)
            stageB(bq * 4 + t + 1);      // async B(t+1), hides under epilogue
            epilogue(bq * 4 + t, acc);
            __syncthreads();             // drains vmcnt -> lB(t+1) ready
        } else {
            epilogue(bq * 4 + t, acc);
        }
    }
}

// ---------------------------------------------------------------------------
// segmax12: identical to the verified r4 version (pure global_load_lds
// table staging; u16-key max chains; sigmoid at the final store).
// ---------------------------------------------------------------------------
__global__ __launch_bounds__(1024) void segmax12_kernel(
    const unsigned short* __restrict__ probs16,
    const int* __restrict__ cur, const unsigned short* __restrict__ ell,
    const int* __restrict__ ovf_cnt, const int* __restrict__ ovf_pairs,
    float* __restrict__ out)
{
    __shared__ unsigned short l[FDIM * 8];   // 80000 B of u16 keys
    int slab = blockIdx.x;
    int b0 = slab * 8;
    int tid = threadIdx.x;
    const unsigned short* src = probs16 + (size_t)slab * FDIM * 8;

    for (int c = tid; c < FDIM; c += 1024) {
        // 16 B per term: direct async copy; lane layout matches (c = base+lane)
        gll16(src + (size_t)c * 8, l + (size_t)c * 8);
    }
    __syncthreads();                         // drains vmcnt -> table resident

    int novf = *ovf_cnt; if (novf > MAXOVF) novf = MAXOVF;

    for (int p0 = tid * 2; p0 < FDIM; p0 += 2048) {
        int p1 = p0 + 1;
        i32x2 dg = *(const i32x2*)(cur + p0);
        upk4 ea = *(const upk4*)(ell + (size_t)p0 * ELLW);
        upk4 eb = *(const upk4*)(ell + (size_t)p1 * ELLW);
        upk8 ma = *(const upk8*)(l + (size_t)ea[0] * 8);
        upk8 mb = *(const upk8*)(l + (size_t)eb[0] * 8);
        ma = umax8(ma, *(const upk8*)(l + (size_t)ea[1] * 8));
        mb = umax8(mb, *(const upk8*)(l + (size_t)eb[1] * 8));
        ma = umax8(ma, *(const upk8*)(l + (size_t)ea[2] * 8));
        mb = umax8(mb, *(const upk8*)(l + (size_t)eb[2] * 8));
        ma = umax8(ma, *(const upk8*)(l + (size_t)ea[3] * 8));
        mb = umax8(mb, *(const upk8*)(l + (size_t)eb[3] * 8));
        if (dg[0] > 4) {
            upk4 e = *(const upk4*)(ell + (size_t)p0 * ELLW + 4);
            ma = umax8(ma, *(const upk8*)(l + (size_t)e[0] * 8));
            ma = umax8(ma, *(const upk8*)(l + (size_t)e[1] * 8));
            ma = umax8(ma, *(const upk8*)(l + (size_t)e[2] * 8));
            ma = umax8(ma, *(const upk8*)(l + (size_t)e[3] * 8));
        }
        if (dg[1] > 4) {
            upk4 e = *(const upk4*)(ell + (size_t)p1 * ELLW + 4);
            mb = umax8(mb, *(const upk8*)(l + (size_t)e[0] * 8));
            mb = umax8(mb, *(const upk8*)(l + (size_t)e[1] * 8));
            mb = umax8(mb, *(const upk8*)(l + (size_t)e[2] * 8));
            mb = umax8(mb, *(const upk8*)(l + (size_t)e[3] * 8));
        }
        if (dg[0] > 8) {
            upk8 e = *(const upk8*)(ell + (size_t)p0 * ELLW + 8);
            #pragma unroll
            for (int j = 0; j < 8; ++j)
                ma = umax8(ma, *(const upk8*)(l + (size_t)e[j] * 8));
        }
        if (dg[1] > 8) {
            upk8 e = *(const upk8*)(ell + (size_t)p1 * ELLW + 8);
            #pragma unroll
            for (int j = 0; j < 8; ++j)
                mb = umax8(mb, *(const upk8*)(l + (size_t)e[j] * 8));
        }
        if (dg[0] > ELLW) {
            for (int i = 0; i < novf; ++i)
                if (ovf_pairs[2 * i] == p0)
                    ma = umax8(ma, *(const upk8*)(l + (size_t)ovf_pairs[2 * i + 1] * 8));
        }
        if (dg[1] > ELLW) {
            for (int i = 0; i < novf; ++i)
                if (ovf_pairs[2 * i] == p1)
                    mb = umax8(mb, *(const upk8*)(l + (size_t)ovf_pairs[2 * i + 1] * 8));
        }
        size_t o = (size_t)b0 * FDIM + p0;
        #pragma unroll
        for (int r = 0; r < 8; ++r) {
            float za = bf2f(unkey(ma[r]));
            float zb = bf2f(unkey(mb[r]));
            f32x2 v2;
            v2[0] = fast_rcp(1.0f + __expf(-za));
            v2[1] = fast_rcp(1.0f + __expf(-zb));
            __builtin_nontemporal_store(v2, (f32x2*)(out + o + (size_t)r * FDIM));
        }
    }
}

// ---------------------------------------------------------------------------
extern "C" void kernel_launch(void* const* d_in, const int* in_sizes, int n_in,
                              void* d_out, int out_size, void* d_ws, size_t ws_size,
                              hipStream_t stream)
{
    const float* x     = (const float*)d_in[0];
    const float* W     = (const float*)d_in[1];
    const float* bias  = (const float*)d_in[2];
    const int*   epar  = (const int*)d_in[3];
    const int*   echild= (const int*)d_in[4];
    float* out = (float*)d_out;

    char* ws = (char*)d_ws;
    size_t off = 0;
    auto alloc = [&](size_t bytes) { size_t o = off; off = (off + bytes + 255) & ~(size_t)255; return o; };
    size_t o_probs  = alloc((size_t)BDIM * FDIM * 2);    // u16 keys
    size_t o_xb     = alloc((size_t)BDIM * CDIM * 2);
    size_t o_wt     = alloc((size_t)FDIM * CDIM * 2);
    size_t o_ell    = alloc((size_t)FDIM * ELLW * 2);
    size_t o_cur    = alloc((size_t)FDIM * 4);
    size_t o_ovfc   = alloc(4);
    size_t o_ovfp   = alloc((size_t)MAXOVF * 8);
    (void)ws_size; (void)in_sizes; (void)n_in; (void)out_size;

    unsigned short* probs16 = (unsigned short*)(ws + o_probs);
    unsigned short* xb      = (unsigned short*)(ws + o_xb);
    unsigned short* wt      = (unsigned short*)(ws + o_wt);
    unsigned short* ell     = (unsigned short*)(ws + o_ell);
    int* cur      = (int*)(ws + o_cur);
    int* ovf_cnt  = (int*)(ws + o_ovfc);
    int* ovf_pairs= (int*)(ws + o_ovfp);

    prep1_kernel<<<1201, 256, 0, stream>>>(x, W, xb, wt, ell, cur, ovf_cnt);
    prep2_kernel<<<79, 256, 0, stream>>>(epar, echild, cur, ell, ovf_cnt, ovf_pairs);
    gemm8k2_kernel<<<128 * NT4, 512, 0, stream>>>(xb, wt, bias, probs16);
    segmax12_kernel<<<BDIM / 8, 1024, 0, stream>>>(probs16, cur, ell,
                                                   ovf_cnt, ovf_pairs, out);
}

// Round 6
// 191.130 us; speedup vs baseline: 1.0420x; 1.0420x over previous
//
#include <hip/hip_runtime.h>
#include <hip/hip_bf16.h>

#define BDIM 16384
#define CDIM 128
#define FDIM 5000
#define EDIM 20000
#define ELLW 16
#define MAXOVF 20000
#define NT4  10       // n-tile QUADS: 40 n-tiles / 4

typedef __attribute__((ext_vector_type(8))) short short8;
typedef __attribute__((ext_vector_type(4))) float f32x4;
typedef __attribute__((ext_vector_type(2))) float f32x2;
typedef __attribute__((ext_vector_type(2))) int i32x2;
typedef __attribute__((ext_vector_type(8))) unsigned short upk8;
typedef __attribute__((ext_vector_type(4))) unsigned short upk4;
typedef __attribute__((ext_vector_type(2))) unsigned int u32x2;

__device__ __forceinline__ unsigned short f2bf(float f) {
    unsigned int u = __builtin_bit_cast(unsigned int, f);
    u = (u + 0x7fffu + ((u >> 16) & 1u)) >> 16;   // RNE
    return (unsigned short)u;
}
__device__ __forceinline__ float bf2f(unsigned short s) {
    unsigned int u = ((unsigned int)s) << 16;
    return __builtin_bit_cast(float, u);
}
__device__ __forceinline__ upk8 umax8(upk8 a, upk8 b) {
#if __has_builtin(__builtin_elementwise_max)
    return __builtin_elementwise_max(a, b);   // 4x v_pk_max_u16
#else
    upk8 r;
    #pragma unroll
    for (int j = 0; j < 8; ++j) r[j] = a[j] > b[j] ? a[j] : b[j];
    return r;
#endif
}
// single v_rcp_f32. VERIFIED WIN round 2: 178.96 -> 159.24 us.
__device__ __forceinline__ float fast_rcp(float x) {
#if __has_builtin(__builtin_amdgcn_rcpf)
    return __builtin_amdgcn_rcpf(x);
#else
    return 1.0f / x;
#endif
}
// order-preserving u16 key of a bf16 pattern h (per 16-bit half, packed u32).
// VERIFIED WIN round 4: 159.24 -> 153.83 us, absmax 0.0059 -> 0.0039.
__device__ __forceinline__ unsigned int key2(unsigned int h) {
    unsigned int t = (h >> 15) & 0x00010001u;
    return h ^ (t * 0x7FFFu + 0x80008000u);
}
// inverse: k -> bf16 bits
__device__ __forceinline__ unsigned short unkey(unsigned short k) {
    unsigned int s = (k >> 15) & 1u;
    return (unsigned short)(k ^ (0x8000u + ((s ^ 1u) * 0x7FFFu)));
}
// async global->LDS, 16B per lane; LDS dest = firstlane base + lane*16
__device__ __forceinline__ void gll16(const unsigned short* g, unsigned short* l) {
    __builtin_amdgcn_global_load_lds(
        (const __attribute__((address_space(1))) void*)g,
        (__attribute__((address_space(3))) void*)l, 16, 0, 0);
}

// ---------------------------------------------------------------------------
// prep1: blocks [0,1024): x f32 -> bf16 (2048 elems/block)
//        blocks [1024,1181): W[k][f] -> Wt[f][k] bf16, LDS-tiled
//        blocks [1181,1201): ELL init (all 16 slots = self), cur=1, ovf=0
// ---------------------------------------------------------------------------
__global__ __launch_bounds__(256) void prep1_kernel(
    const float* __restrict__ x, const float* __restrict__ W,
    unsigned short* __restrict__ xb, unsigned short* __restrict__ wt,
    unsigned short* __restrict__ ell, int* __restrict__ cur,
    int* __restrict__ ovf_cnt)
{
    __shared__ float lt[128][33];
    int bid = blockIdx.x, tid = threadIdx.x;
    if (bid < 1024) {
        size_t base = (size_t)bid * 2048 + (size_t)tid * 8;
        const f32x4* p = (const f32x4*)(x + base);
        f32x4 v0 = p[0], v1 = p[1];
        short8 o;
        o[0] = (short)f2bf(v0[0]); o[1] = (short)f2bf(v0[1]);
        o[2] = (short)f2bf(v0[2]); o[3] = (short)f2bf(v0[3]);
        o[4] = (short)f2bf(v1[0]); o[5] = (short)f2bf(v1[1]);
        o[6] = (short)f2bf(v1[2]); o[7] = (short)f2bf(v1[3]);
        *(short8*)(xb + base) = o;
    } else if (bid < 1181) {
        int f0 = (bid - 1024) * 32;
        int f_l = tid & 31, k0 = (tid >> 5) * 16;
        #pragma unroll
        for (int i = 0; i < 16; ++i) {
            int f = f0 + f_l;
            lt[k0 + i][f_l] = (f < FDIM) ? W[(size_t)(k0 + i) * FDIM + f] : 0.f;
        }
        __syncthreads();
        int f_l2 = tid >> 3, ks = (tid & 7) * 16;
        int f = f0 + f_l2;
        if (f < FDIM) {
            short8 o0, o1;
            #pragma unroll
            for (int j = 0; j < 8; ++j) o0[j] = (short)f2bf(lt[ks + j][f_l2]);
            #pragma unroll
            for (int j = 0; j < 8; ++j) o1[j] = (short)f2bf(lt[ks + 8 + j][f_l2]);
            *(short8*)(wt + (size_t)f * 128 + ks)     = o0;
            *(short8*)(wt + (size_t)f * 128 + ks + 8) = o1;
        }
    } else {
        int p = (bid - 1181) * 256 + tid;
        if (p < FDIM) {
            upk8 s;
            #pragma unroll
            for (int j = 0; j < 8; ++j) s[j] = (unsigned short)p;
            *(upk8*)(ell + (size_t)p * ELLW)     = s;
            *(upk8*)(ell + (size_t)p * ELLW + 8) = s;
            cur[p] = 1;
        }
        if (p == FDIM) *ovf_cnt = 0;
    }
}

// ---------------------------------------------------------------------------
// prep2: scatter children into ELL slots 1.. (order irrelevant: max).
// ---------------------------------------------------------------------------
__global__ __launch_bounds__(256) void prep2_kernel(
    const int* __restrict__ epar, const int* __restrict__ echild,
    int* __restrict__ cur, unsigned short* __restrict__ ell,
    int* __restrict__ ovf_cnt, int* __restrict__ ovf_pairs)
{
    int i = blockIdx.x * 256 + threadIdx.x;
    if (i < EDIM) {
        int p = epar[i], c = echild[i];
        if (p != c) {
            int pos = atomicAdd(&cur[p], 1);
            if (pos < ELLW) {
                ell[(size_t)p * ELLW + pos] = (unsigned short)c;
            } else {
                int j = atomicAdd(ovf_cnt, 1);
                if (j < MAXOVF) { ovf_pairs[2 * j] = p; ovf_pairs[2 * j + 1] = c; }
            }
        }
    }
}

// ---------------------------------------------------------------------------
// gemm8k: EXACT r4 verified version (153.83 us pipeline). A fragments are
// re-read from lA each n-tile (af-hoist VERIFIED REGRESSION r1/r5: 64-VGPR
// persistent state spills under the (512,4) 128-VGPR cap).
// MEASUREMENT THIS ROUND: launched TWICE (idempotent) so the total dur
// prices the gemm phase: gemm_us = dur - 153.8.
// ---------------------------------------------------------------------------
__global__ __launch_bounds__(512, 4) void gemm8k_kernel(
    const unsigned short* __restrict__ xb,   // [BDIM][128] bf16
    const unsigned short* __restrict__ wt,   // [FDIM][128] bf16
    const float* __restrict__ bias,
    unsigned short* __restrict__ probs16)    // [BDIM/8][FDIM][8] u16 keys
{
    __shared__ unsigned short lA[128 * 128];
    __shared__ unsigned short lB[128 * 128];

    int bid0 = blockIdx.x;
    int bid  = (bid0 & 7) * (128 * NT4 / 8) + (bid0 >> 3);   // XCD swizzle
    int bm = bid / NT4, bq = bid % NT4;
    int tid = threadIdx.x;
    int lane = tid & 63, w = tid >> 6;       // 8 waves
    int wm = w >> 2, wn = w & 3;
    int g = lane >> 4, lr = lane & 15;
    int lrow = lane >> 4;                    // row within 4-row chunk
    int lcol = (lane & 15) << 4;             // byte col

    auto stageA = [&]() {
        #pragma unroll
        for (int it = 0; it < 4; ++it) {
            int ci = w * 4 + it;             // chunk 0..31
            int row = ci * 4 + lrow;
            int sw = lcol ^ ((row & 7) << 4);
            gll16(xb + ((size_t)(bm * 128 + row) << 7) + (sw >> 1),
                  lA + ci * 512);
        }
    };
    auto stageB = [&](int bn) {
        #pragma unroll
        for (int it = 0; it < 4; ++it) {
            int ci = w * 4 + it;
            int row = ci * 4 + lrow;
            int sw = lcol ^ ((row & 7) << 4);
            gll16(wt + ((size_t)(bn * 128 + row) << 7) + (sw >> 1),
                  lB + ci * 512);
        }
    };
    auto compute = [&](f32x4 (&acc)[4][2]) {
        #pragma unroll
        for (int ks = 0; ks < 4; ++ks) {
            int cbk = ks * 64 + g * 16;
            short8 af[4], bf[2];
            #pragma unroll
            for (int mi = 0; mi < 4; ++mi) {
                int row = wm * 64 + mi * 16 + lr;
                af[mi] = *(const short8*)((const char*)lA + row * 256 + (cbk ^ ((row & 7) << 4)));
            }
            #pragma unroll
            for (int nj = 0; nj < 2; ++nj) {
                int row = wn * 32 + nj * 16 + lr;
                bf[nj] = *(const short8*)((const char*)lB + row * 256 + (cbk ^ ((row & 7) << 4)));
            }
            #pragma unroll
            for (int mi = 0; mi < 4; ++mi)
                #pragma unroll
                for (int nj = 0; nj < 2; ++nj)
                    acc[mi][nj] = __builtin_amdgcn_mfma_f32_16x16x32_bf16(
                        af[mi], bf[nj], acc[mi][nj], 0, 0, 0);
        }
    };
    auto epilogue = [&](int bn, f32x4 (&acc)[4][2]) {
        #pragma unroll
        for (int nj = 0; nj < 2; ++nj) {
            int f = bn * 128 + wn * 32 + nj * 16 + lr;
            bool ok = (f < FDIM);
            float bb = ok ? bias[f] : 0.f;
            #pragma unroll
            for (int mi = 0; mi < 4; ++mi) {
                float z0 = acc[mi][nj][0] + bb;
                float z1 = acc[mi][nj][1] + bb;
                float z2 = acc[mi][nj][2] + bb;
                float z3 = acc[mi][nj][3] + bb;
                unsigned int h01, h23;   // packed bf16 (low = first operand)
                asm("v_cvt_pk_bf16_f32 %0, %1, %2" : "=v"(h01) : "v"(z0), "v"(z1));
                asm("v_cvt_pk_bf16_f32 %0, %1, %2" : "=v"(h23) : "v"(z2), "v"(z3));
                u32x2 st;
                st[0] = key2(h01);
                st[1] = key2(h23);
                if (ok) {
                    int slab = bm * 16 + wm * 8 + mi * 2 + (g >> 1);
                    *(u32x2*)(probs16 + ((size_t)slab * FDIM + f) * 8 + (g & 1) * 4) = st;
                }
            }
        }
    };

    stageA();
    stageB(bq * 4);
    __syncthreads();                     // drains vmcnt -> tiles resident

    f32x4 zero = {0.f, 0.f, 0.f, 0.f};
    for (int t = 0; t < 4; ++t) {
        f32x4 acc[4][2];
        #pragma unroll
        for (int mi = 0; mi < 4; ++mi) { acc[mi][0] = zero; acc[mi][1] = zero; }
        compute(acc);
        if (t < 3) {
            __syncthreads();             // all waves done reading lB(t)
            stageB(bq * 4 + t + 1);      // async B(t+1), hides under epilogue
            epilogue(bq * 4 + t, acc);
            __syncthreads();             // drains vmcnt -> lB(t+1) ready
        } else {
            epilogue(bq * 4 + t, acc);
        }
    }
}

// ---------------------------------------------------------------------------
// segmax12: EXACT r4 verified version (pure global_load_lds table staging;
// u16-key max chains; sigmoid at the final store).
// ---------------------------------------------------------------------------
__global__ __launch_bounds__(1024) void segmax12_kernel(
    const unsigned short* __restrict__ probs16,
    const int* __restrict__ cur, const unsigned short* __restrict__ ell,
    const int* __restrict__ ovf_cnt, const int* __restrict__ ovf_pairs,
    float* __restrict__ out)
{
    __shared__ unsigned short l[FDIM * 8];   // 80000 B of u16 keys
    int slab = blockIdx.x;
    int b0 = slab * 8;
    int tid = threadIdx.x;
    const unsigned short* src = probs16 + (size_t)slab * FDIM * 8;

    for (int c = tid; c < FDIM; c += 1024) {
        // 16 B per term: direct async copy; lane layout matches (c = base+lane)
        gll16(src + (size_t)c * 8, l + (size_t)c * 8);
    }
    __syncthreads();                         // drains vmcnt -> table resident

    int novf = *ovf_cnt; if (novf > MAXOVF) novf = MAXOVF;

    for (int p0 = tid * 2; p0 < FDIM; p0 += 2048) {
        int p1 = p0 + 1;
        i32x2 dg = *(const i32x2*)(cur + p0);
        upk4 ea = *(const upk4*)(ell + (size_t)p0 * ELLW);
        upk4 eb = *(const upk4*)(ell + (size_t)p1 * ELLW);
        upk8 ma = *(const upk8*)(l + (size_t)ea[0] * 8);
        upk8 mb = *(const upk8*)(l + (size_t)eb[0] * 8);
        ma = umax8(ma, *(const upk8*)(l + (size_t)ea[1] * 8));
        mb = umax8(mb, *(const upk8*)(l + (size_t)eb[1] * 8));
        ma = umax8(ma, *(const upk8*)(l + (size_t)ea[2] * 8));
        mb = umax8(mb, *(const upk8*)(l + (size_t)eb[2] * 8));
        ma = umax8(ma, *(const upk8*)(l + (size_t)ea[3] * 8));
        mb = umax8(mb, *(const upk8*)(l + (size_t)eb[3] * 8));
        if (dg[0] > 4) {
            upk4 e = *(const upk4*)(ell + (size_t)p0 * ELLW + 4);
            ma = umax8(ma, *(const upk8*)(l + (size_t)e[0] * 8));
            ma = umax8(ma, *(const upk8*)(l + (size_t)e[1] * 8));
            ma = umax8(ma, *(const upk8*)(l + (size_t)e[2] * 8));
            ma = umax8(ma, *(const upk8*)(l + (size_t)e[3] * 8));
        }
        if (dg[1] > 4) {
            upk4 e = *(const upk4*)(ell + (size_t)p1 * ELLW + 4);
            mb = umax8(mb, *(const upk8*)(l + (size_t)e[0] * 8));
            mb = umax8(mb, *(const upk8*)(l + (size_t)e[1] * 8));
            mb = umax8(mb, *(const upk8*)(l + (size_t)e[2] * 8));
            mb = umax8(mb, *(const upk8*)(l + (size_t)e[3] * 8));
        }
        if (dg[0] > 8) {
            upk8 e = *(const upk8*)(ell + (size_t)p0 * ELLW + 8);
            #pragma unroll
            for (int j = 0; j < 8; ++j)
                ma = umax8(ma, *(const upk8*)(l + (size_t)e[j] * 8));
        }
        if (dg[1] > 8) {
            upk8 e = *(const upk8*)(ell + (size_t)p1 * ELLW + 8);
            #pragma unroll
            for (int j = 0; j < 8; ++j)
                mb = umax8(mb, *(const upk8*)(l + (size_t)e[j] * 8));
        }
        if (dg[0] > ELLW) {
            for (int i = 0; i < novf; ++i)
                if (ovf_pairs[2 * i] == p0)
                    ma = umax8(ma, *(const upk8*)(l + (size_t)ovf_pairs[2 * i + 1] * 8));
        }
        if (dg[1] > ELLW) {
            for (int i = 0; i < novf; ++i)
                if (ovf_pairs[2 * i] == p1)
                    mb = umax8(mb, *(const upk8*)(l + (size_t)ovf_pairs[2 * i + 1] * 8));
        }
        size_t o = (size_t)b0 * FDIM + p0;
        #pragma unroll
        for (int r = 0; r < 8; ++r) {
            float za = bf2f(unkey(ma[r]));
            float zb = bf2f(unkey(mb[r]));
            f32x2 v2;
            v2[0] = fast_rcp(1.0f + __expf(-za));
            v2[1] = fast_rcp(1.0f + __expf(-zb));
            __builtin_nontemporal_store(v2, (f32x2*)(out + o + (size_t)r * FDIM));
        }
    }
}

// ---------------------------------------------------------------------------
extern "C" void kernel_launch(void* const* d_in, const int* in_sizes, int n_in,
                              void* d_out, int out_size, void* d_ws, size_t ws_size,
                              hipStream_t stream)
{
    const float* x     = (const float*)d_in[0];
    const float* W     = (const float*)d_in[1];
    const float* bias  = (const float*)d_in[2];
    const int*   epar  = (const int*)d_in[3];
    const int*   echild= (const int*)d_in[4];
    float* out = (float*)d_out;

    char* ws = (char*)d_ws;
    size_t off = 0;
    auto alloc = [&](size_t bytes) { size_t o = off; off = (off + bytes + 255) & ~(size_t)255; return o; };
    size_t o_probs  = alloc((size_t)BDIM * FDIM * 2);    // u16 keys
    size_t o_xb     = alloc((size_t)BDIM * CDIM * 2);
    size_t o_wt     = alloc((size_t)FDIM * CDIM * 2);
    size_t o_ell    = alloc((size_t)FDIM * ELLW * 2);
    size_t o_cur    = alloc((size_t)FDIM * 4);
    size_t o_ovfc   = alloc(4);
    size_t o_ovfp   = alloc((size_t)MAXOVF * 8);
    (void)ws_size; (void)in_sizes; (void)n_in; (void)out_size;

    unsigned short* probs16 = (unsigned short*)(ws + o_probs);
    unsigned short* xb      = (unsigned short*)(ws + o_xb);
    unsigned short* wt      = (unsigned short*)(ws + o_wt);
    unsigned short* ell     = (unsigned short*)(ws + o_ell);
    int* cur      = (int*)(ws + o_cur);
    int* ovf_cnt  = (int*)(ws + o_ovfc);
    int* ovf_pairs= (int*)(ws + o_ovfp);

    prep1_kernel<<<1201, 256, 0, stream>>>(x, W, xb, wt, ell, cur, ovf_cnt);
    prep2_kernel<<<79, 256, 0, stream>>>(epar, echild, cur, ell, ovf_cnt, ovf_pairs);
    gemm8k_kernel<<<128 * NT4, 512, 0, stream>>>(xb, wt, bias, probs16);
    // MEASUREMENT (this round only): second identical launch prices the
    // gemm phase. Idempotent: rewrites identical probs16 bytes.
    gemm8k_kernel<<<128 * NT4, 512, 0, stream>>>(xb, wt, bias, probs16);
    segmax12_kernel<<<BDIM / 8, 1024, 0, stream>>>(probs16, cur, ell,
                                                   ovf_cnt, ovf_pairs, out);
}

// Round 7
// 156.504 us; speedup vs baseline: 1.2726x; 1.2212x over previous
//
#include <hip/hip_runtime.h>
#include <hip/hip_bf16.h>

#define BDIM 16384
#define CDIM 128
#define FDIM 5000
#define EDIM 20000
#define ELLW 16
#define MAXOVF 20000
#define NT4  10       // n-tile QUADS: 40 n-tiles / 4

typedef __attribute__((ext_vector_type(8))) short short8;
typedef __attribute__((ext_vector_type(4))) float f32x4;
typedef __attribute__((ext_vector_type(2))) float f32x2;
typedef __attribute__((ext_vector_type(2))) int i32x2;
typedef __attribute__((ext_vector_type(8))) unsigned short upk8;
typedef __attribute__((ext_vector_type(4))) unsigned short upk4;
typedef __attribute__((ext_vector_type(2))) unsigned int u32x2;

__device__ __forceinline__ unsigned short f2bf(float f) {
    unsigned int u = __builtin_bit_cast(unsigned int, f);
    u = (u + 0x7fffu + ((u >> 16) & 1u)) >> 16;   // RNE
    return (unsigned short)u;
}
__device__ __forceinline__ float bf2f(unsigned short s) {
    unsigned int u = ((unsigned int)s) << 16;
    return __builtin_bit_cast(float, u);
}
__device__ __forceinline__ upk8 umax8(upk8 a, upk8 b) {
#if __has_builtin(__builtin_elementwise_max)
    return __builtin_elementwise_max(a, b);   // 4x v_pk_max_u16
#else
    upk8 r;
    #pragma unroll
    for (int j = 0; j < 8; ++j) r[j] = a[j] > b[j] ? a[j] : b[j];
    return r;
#endif
}
// single v_rcp_f32. VERIFIED WIN round 2: 178.96 -> 159.24 us.
__device__ __forceinline__ float fast_rcp(float x) {
#if __has_builtin(__builtin_amdgcn_rcpf)
    return __builtin_amdgcn_rcpf(x);
#else
    return 1.0f / x;
#endif
}
// order-preserving u16 key of a bf16 pattern h (per 16-bit half, packed u32).
// VERIFIED WIN round 4: 159.24 -> 153.83 us, absmax 0.0059 -> 0.0039.
__device__ __forceinline__ unsigned int key2(unsigned int h) {
    unsigned int t = (h >> 15) & 0x00010001u;
    return h ^ (t * 0x7FFFu + 0x80008000u);
}
// inverse: k -> bf16 bits
__device__ __forceinline__ unsigned short unkey(unsigned short k) {
    unsigned int s = (k >> 15) & 1u;
    return (unsigned short)(k ^ (0x8000u + ((s ^ 1u) * 0x7FFFu)));
}
__device__ __forceinline__ float sigk(unsigned short k) {
    return fast_rcp(1.0f + __expf(-bf2f(unkey(k))));
}
// async global->LDS, 16B per lane; LDS dest = firstlane base + lane*16
__device__ __forceinline__ void gll16(const unsigned short* g, unsigned short* l) {
    __builtin_amdgcn_global_load_lds(
        (const __attribute__((address_space(1))) void*)g,
        (__attribute__((address_space(3))) void*)l, 16, 0, 0);
}

// ---------------------------------------------------------------------------
// prep1: blocks [0,1024): x f32 -> bf16 (2048 elems/block)
//        blocks [1024,1181): W[k][f] -> Wt[f][k] bf16, LDS-tiled
//        blocks [1181,1201): ELL init (all 16 slots = self), cur=1, ovf=0
// ---------------------------------------------------------------------------
__global__ __launch_bounds__(256) void prep1_kernel(
    const float* __restrict__ x, const float* __restrict__ W,
    unsigned short* __restrict__ xb, unsigned short* __restrict__ wt,
    unsigned short* __restrict__ ell, int* __restrict__ cur,
    int* __restrict__ ovf_cnt)
{
    __shared__ float lt[128][33];
    int bid = blockIdx.x, tid = threadIdx.x;
    if (bid < 1024) {
        size_t base = (size_t)bid * 2048 + (size_t)tid * 8;
        const f32x4* p = (const f32x4*)(x + base);
        f32x4 v0 = p[0], v1 = p[1];
        short8 o;
        o[0] = (short)f2bf(v0[0]); o[1] = (short)f2bf(v0[1]);
        o[2] = (short)f2bf(v0[2]); o[3] = (short)f2bf(v0[3]);
        o[4] = (short)f2bf(v1[0]); o[5] = (short)f2bf(v1[1]);
        o[6] = (short)f2bf(v1[2]); o[7] = (short)f2bf(v1[3]);
        *(short8*)(xb + base) = o;
    } else if (bid < 1181) {
        int f0 = (bid - 1024) * 32;
        int f_l = tid & 31, k0 = (tid >> 5) * 16;
        #pragma unroll
        for (int i = 0; i < 16; ++i) {
            int f = f0 + f_l;
            lt[k0 + i][f_l] = (f < FDIM) ? W[(size_t)(k0 + i) * FDIM + f] : 0.f;
        }
        __syncthreads();
        int f_l2 = tid >> 3, ks = (tid & 7) * 16;
        int f = f0 + f_l2;
        if (f < FDIM) {
            short8 o0, o1;
            #pragma unroll
            for (int j = 0; j < 8; ++j) o0[j] = (short)f2bf(lt[ks + j][f_l2]);
            #pragma unroll
            for (int j = 0; j < 8; ++j) o1[j] = (short)f2bf(lt[ks + 8 + j][f_l2]);
            *(short8*)(wt + (size_t)f * 128 + ks)     = o0;
            *(short8*)(wt + (size_t)f * 128 + ks + 8) = o1;
        }
    } else {
        int p = (bid - 1181) * 256 + tid;
        if (p < FDIM) {
            upk8 s;
            #pragma unroll
            for (int j = 0; j < 8; ++j) s[j] = (unsigned short)p;
            *(upk8*)(ell + (size_t)p * ELLW)     = s;
            *(upk8*)(ell + (size_t)p * ELLW + 8) = s;
            cur[p] = 1;
        }
        if (p == FDIM) *ovf_cnt = 0;
    }
}

// ---------------------------------------------------------------------------
// prep2: scatter children into ELL slots 1.. (order irrelevant: max).
// ---------------------------------------------------------------------------
__global__ __launch_bounds__(256) void prep2_kernel(
    const int* __restrict__ epar, const int* __restrict__ echild,
    int* __restrict__ cur, unsigned short* __restrict__ ell,
    int* __restrict__ ovf_cnt, int* __restrict__ ovf_pairs)
{
    int i = blockIdx.x * 256 + threadIdx.x;
    if (i < EDIM) {
        int p = epar[i], c = echild[i];
        if (p != c) {
            int pos = atomicAdd(&cur[p], 1);
            if (pos < ELLW) {
                ell[(size_t)p * ELLW + pos] = (unsigned short)c;
            } else {
                int j = atomicAdd(ovf_cnt, 1);
                if (j < MAXOVF) { ovf_pairs[2 * j] = p; ovf_pairs[2 * j + 1] = c; }
            }
        }
    }
}

// ---------------------------------------------------------------------------
// gemm8k: EXACT r4 verified version (153.83 us pipeline, gemm ~37-40 us
// measured r6). Single launch again.
// ---------------------------------------------------------------------------
__global__ __launch_bounds__(512, 4) void gemm8k_kernel(
    const unsigned short* __restrict__ xb,   // [BDIM][128] bf16
    const unsigned short* __restrict__ wt,   // [FDIM][128] bf16
    const float* __restrict__ bias,
    unsigned short* __restrict__ probs16)    // [BDIM/8][FDIM][8] u16 keys
{
    __shared__ unsigned short lA[128 * 128];
    __shared__ unsigned short lB[128 * 128];

    int bid0 = blockIdx.x;
    int bid  = (bid0 & 7) * (128 * NT4 / 8) + (bid0 >> 3);   // XCD swizzle
    int bm = bid / NT4, bq = bid % NT4;
    int tid = threadIdx.x;
    int lane = tid & 63, w = tid >> 6;       // 8 waves
    int wm = w >> 2, wn = w & 3;
    int g = lane >> 4, lr = lane & 15;
    int lrow = lane >> 4;                    // row within 4-row chunk
    int lcol = (lane & 15) << 4;             // byte col

    auto stageA = [&]() {
        #pragma unroll
        for (int it = 0; it < 4; ++it) {
            int ci = w * 4 + it;             // chunk 0..31
            int row = ci * 4 + lrow;
            int sw = lcol ^ ((row & 7) << 4);
            gll16(xb + ((size_t)(bm * 128 + row) << 7) + (sw >> 1),
                  lA + ci * 512);
        }
    };
    auto stageB = [&](int bn) {
        #pragma unroll
        for (int it = 0; it < 4; ++it) {
            int ci = w * 4 + it;
            int row = ci * 4 + lrow;
            int sw = lcol ^ ((row & 7) << 4);
            gll16(wt + ((size_t)(bn * 128 + row) << 7) + (sw >> 1),
                  lB + ci * 512);
        }
    };
    auto compute = [&](f32x4 (&acc)[4][2]) {
        #pragma unroll
        for (int ks = 0; ks < 4; ++ks) {
            int cbk = ks * 64 + g * 16;
            short8 af[4], bf[2];
            #pragma unroll
            for (int mi = 0; mi < 4; ++mi) {
                int row = wm * 64 + mi * 16 + lr;
                af[mi] = *(const short8*)((const char*)lA + row * 256 + (cbk ^ ((row & 7) << 4)));
            }
            #pragma unroll
            for (int nj = 0; nj < 2; ++nj) {
                int row = wn * 32 + nj * 16 + lr;
                bf[nj] = *(const short8*)((const char*)lB + row * 256 + (cbk ^ ((row & 7) << 4)));
            }
            #pragma unroll
            for (int mi = 0; mi < 4; ++mi)
                #pragma unroll
                for (int nj = 0; nj < 2; ++nj)
                    acc[mi][nj] = __builtin_amdgcn_mfma_f32_16x16x32_bf16(
                        af[mi], bf[nj], acc[mi][nj], 0, 0, 0);
        }
    };
    auto epilogue = [&](int bn, f32x4 (&acc)[4][2]) {
        #pragma unroll
        for (int nj = 0; nj < 2; ++nj) {
            int f = bn * 128 + wn * 32 + nj * 16 + lr;
            bool ok = (f < FDIM);
            float bb = ok ? bias[f] : 0.f;
            #pragma unroll
            for (int mi = 0; mi < 4; ++mi) {
                float z0 = acc[mi][nj][0] + bb;
                float z1 = acc[mi][nj][1] + bb;
                float z2 = acc[mi][nj][2] + bb;
                float z3 = acc[mi][nj][3] + bb;
                unsigned int h01, h23;   // packed bf16 (low = first operand)
                asm("v_cvt_pk_bf16_f32 %0, %1, %2" : "=v"(h01) : "v"(z0), "v"(z1));
                asm("v_cvt_pk_bf16_f32 %0, %1, %2" : "=v"(h23) : "v"(z2), "v"(z3));
                u32x2 st;
                st[0] = key2(h01);
                st[1] = key2(h23);
                if (ok) {
                    int slab = bm * 16 + wm * 8 + mi * 2 + (g >> 1);
                    *(u32x2*)(probs16 + ((size_t)slab * FDIM + f) * 8 + (g & 1) * 4) = st;
                }
            }
        }
    };

    stageA();
    stageB(bq * 4);
    __syncthreads();                     // drains vmcnt -> tiles resident

    f32x4 zero = {0.f, 0.f, 0.f, 0.f};
    for (int t = 0; t < 4; ++t) {
        f32x4 acc[4][2];
        #pragma unroll
        for (int mi = 0; mi < 4; ++mi) { acc[mi][0] = zero; acc[mi][1] = zero; }
        compute(acc);
        if (t < 3) {
            __syncthreads();             // all waves done reading lB(t)
            stageB(bq * 4 + t + 1);      // async B(t+1), hides under epilogue
            epilogue(bq * 4 + t, acc);
            __syncthreads();             // drains vmcnt -> lB(t+1) ready
        } else {
            epilogue(bq * 4 + t, acc);
        }
    }
}

// ---------------------------------------------------------------------------
// segmax13: ILP restructure of the verified segmax12. Theory: seg is
// LATENCY-bound (serial chain: ell load -> dependent LDS gathers -> umax,
// x2.44 dynamic-trip iterations, no pipelining). For 1024 threads, pairs
// 2t and 2t+2048 exist for EVERY thread -> main path processes 4 parents
// with full cross-parent ILP (all ell rows as one b128 each covering
// slots 0-7, 16 independent LDS gathers in flight); 2-parent tail for
// tid<452 covers [4096,5000). launch_bounds(1024,8) pins 64-VGPR /
// 2-blocks-per-CU (r4's proven occupancy). Math identical to segmax12.
// ---------------------------------------------------------------------------
__global__ __launch_bounds__(1024, 8) void segmax13_kernel(
    const unsigned short* __restrict__ probs16,
    const int* __restrict__ cur, const unsigned short* __restrict__ ell,
    const int* __restrict__ ovf_cnt, const int* __restrict__ ovf_pairs,
    float* __restrict__ out)
{
    __shared__ unsigned short l[FDIM * 8];   // 80000 B of u16 keys
    int slab = blockIdx.x;
    int b0 = slab * 8;
    int tid = threadIdx.x;
    const unsigned short* src = probs16 + (size_t)slab * FDIM * 8;

    for (int c = tid; c < FDIM; c += 1024) {
        gll16(src + (size_t)c * 8, l + (size_t)c * 8);
    }
    __syncthreads();                         // drains vmcnt -> table resident

    int novf = *ovf_cnt; if (novf > MAXOVF) novf = MAXOVF;

    // ---- main: 4 parents (2t, 2t+1, 2t+2048, 2t+2049), cross-parent ILP ----
    {
        int p0 = tid * 2;
        int pb = p0 + 2048;                  // 2t+2048 <= 4094 < FDIM always
        i32x2 dgA = *(const i32x2*)(cur + p0);
        i32x2 dgB = *(const i32x2*)(cur + pb);
        upk8 er[4];
        er[0] = *(const upk8*)(ell + (size_t)p0 * ELLW);        // slots 0-7
        er[1] = *(const upk8*)(ell + (size_t)(p0 + 1) * ELLW);
        er[2] = *(const upk8*)(ell + (size_t)pb * ELLW);
        er[3] = *(const upk8*)(ell + (size_t)(pb + 1) * ELLW);
        int dg[4] = { dgA[0], dgA[1], dgB[0], dgB[1] };

        upk8 m[4];
        #pragma unroll
        for (int j = 0; j < 4; ++j)
            m[j] = *(const upk8*)(l + (size_t)er[j][0] * 8);
        #pragma unroll
        for (int s = 1; s < 4; ++s)
            #pragma unroll
            for (int j = 0; j < 4; ++j)
                m[j] = umax8(m[j], *(const upk8*)(l + (size_t)er[j][s] * 8));

        #pragma unroll
        for (int j = 0; j < 4; ++j) {
            if (dg[j] > 4) {                 // slots 4-7 already in er[j]
                m[j] = umax8(m[j], *(const upk8*)(l + (size_t)er[j][4] * 8));
                m[j] = umax8(m[j], *(const upk8*)(l + (size_t)er[j][5] * 8));
                m[j] = umax8(m[j], *(const upk8*)(l + (size_t)er[j][6] * 8));
                m[j] = umax8(m[j], *(const upk8*)(l + (size_t)er[j][7] * 8));
            }
        }
        #pragma unroll
        for (int j = 0; j < 4; ++j) {
            int pj = (j < 2) ? (p0 + j) : (pb + (j - 2));
            if (dg[j] > 8) {
                upk8 e2 = *(const upk8*)(ell + (size_t)pj * ELLW + 8);
                #pragma unroll
                for (int k = 0; k < 8; ++k)
                    m[j] = umax8(m[j], *(const upk8*)(l + (size_t)e2[k] * 8));
            }
            if (dg[j] > ELLW) {
                for (int i = 0; i < novf; ++i)
                    if (ovf_pairs[2 * i] == pj)
                        m[j] = umax8(m[j], *(const upk8*)(l + (size_t)ovf_pairs[2 * i + 1] * 8));
            }
        }

        size_t o = (size_t)b0 * FDIM;
        #pragma unroll
        for (int r = 0; r < 8; ++r) {
            f32x2 va, vb;
            va[0] = sigk(m[0][r]);
            va[1] = sigk(m[1][r]);
            vb[0] = sigk(m[2][r]);
            vb[1] = sigk(m[3][r]);
            __builtin_nontemporal_store(va, (f32x2*)(out + o + (size_t)r * FDIM + p0));
            __builtin_nontemporal_store(vb, (f32x2*)(out + o + (size_t)r * FDIM + pb));
        }
    }

    // ---- tail: pair (2t+4096, 2t+4097), only for tid < 452 ----
    int pt = tid * 2 + 4096;
    if (pt < FDIM) {
        int p1 = pt + 1;
        i32x2 dg = *(const i32x2*)(cur + pt);
        upk8 ea = *(const upk8*)(ell + (size_t)pt * ELLW);   // slots 0-7
        upk8 eb = *(const upk8*)(ell + (size_t)p1 * ELLW);
        upk8 ma = *(const upk8*)(l + (size_t)ea[0] * 8);
        upk8 mb = *(const upk8*)(l + (size_t)eb[0] * 8);
        ma = umax8(ma, *(const upk8*)(l + (size_t)ea[1] * 8));
        mb = umax8(mb, *(const upk8*)(l + (size_t)eb[1] * 8));
        ma = umax8(ma, *(const upk8*)(l + (size_t)ea[2] * 8));
        mb = umax8(mb, *(const upk8*)(l + (size_t)eb[2] * 8));
        ma = umax8(ma, *(const upk8*)(l + (size_t)ea[3] * 8));
        mb = umax8(mb, *(const upk8*)(l + (size_t)eb[3] * 8));
        if (dg[0] > 4) {
            ma = umax8(ma, *(const upk8*)(l + (size_t)ea[4] * 8));
            ma = umax8(ma, *(const upk8*)(l + (size_t)ea[5] * 8));
            ma = umax8(ma, *(const upk8*)(l + (size_t)ea[6] * 8));
            ma = umax8(ma, *(const upk8*)(l + (size_t)ea[7] * 8));
        }
        if (dg[1] > 4) {
            mb = umax8(mb, *(const upk8*)(l + (size_t)eb[4] * 8));
            mb = umax8(mb, *(const upk8*)(l + (size_t)eb[5] * 8));
            mb = umax8(mb, *(const upk8*)(l + (size_t)eb[6] * 8));
            mb = umax8(mb, *(const upk8*)(l + (size_t)eb[7] * 8));
        }
        if (dg[0] > 8) {
            upk8 e = *(const upk8*)(ell + (size_t)pt * ELLW + 8);
            #pragma unroll
            for (int k = 0; k < 8; ++k)
                ma = umax8(ma, *(const upk8*)(l + (size_t)e[k] * 8));
        }
        if (dg[1] > 8) {
            upk8 e = *(const upk8*)(ell + (size_t)p1 * ELLW + 8);
            #pragma unroll
            for (int k = 0; k < 8; ++k)
                mb = umax8(mb, *(const upk8*)(l + (size_t)e[k] * 8));
        }
        if (dg[0] > ELLW) {
            for (int i = 0; i < novf; ++i)
                if (ovf_pairs[2 * i] == pt)
                    ma = umax8(ma, *(const upk8*)(l + (size_t)ovf_pairs[2 * i + 1] * 8));
        }
        if (dg[1] > ELLW) {
            for (int i = 0; i < novf; ++i)
                if (ovf_pairs[2 * i] == p1)
                    mb = umax8(mb, *(const upk8*)(l + (size_t)ovf_pairs[2 * i + 1] * 8));
        }
        size_t o = (size_t)b0 * FDIM + pt;
        #pragma unroll
        for (int r = 0; r < 8; ++r) {
            f32x2 v2;
            v2[0] = sigk(ma[r]);
            v2[1] = sigk(mb[r]);
            __builtin_nontemporal_store(v2, (f32x2*)(out + o + (size_t)r * FDIM));
        }
    }
}

// ---------------------------------------------------------------------------
extern "C" void kernel_launch(void* const* d_in, const int* in_sizes, int n_in,
                              void* d_out, int out_size, void* d_ws, size_t ws_size,
                              hipStream_t stream)
{
    const float* x     = (const float*)d_in[0];
    const float* W     = (const float*)d_in[1];
    const float* bias  = (const float*)d_in[2];
    const int*   epar  = (const int*)d_in[3];
    const int*   echild= (const int*)d_in[4];
    float* out = (float*)d_out;

    char* ws = (char*)d_ws;
    size_t off = 0;
    auto alloc = [&](size_t bytes) { size_t o = off; off = (off + bytes + 255) & ~(size_t)255; return o; };
    size_t o_probs  = alloc((size_t)BDIM * FDIM * 2);    // u16 keys
    size_t o_xb     = alloc((size_t)BDIM * CDIM * 2);
    size_t o_wt     = alloc((size_t)FDIM * CDIM * 2);
    size_t o_ell    = alloc((size_t)FDIM * ELLW * 2);
    size_t o_cur    = alloc((size_t)FDIM * 4);
    size_t o_ovfc   = alloc(4);
    size_t o_ovfp   = alloc((size_t)MAXOVF * 8);
    (void)ws_size; (void)in_sizes; (void)n_in; (void)out_size;

    unsigned short* probs16 = (unsigned short*)(ws + o_probs);
    unsigned short* xb      = (unsigned short*)(ws + o_xb);
    unsigned short* wt      = (unsigned short*)(ws + o_wt);
    unsigned short* ell     = (unsigned short*)(ws + o_ell);
    int* cur      = (int*)(ws + o_cur);
    int* ovf_cnt  = (int*)(ws + o_ovfc);
    int* ovf_pairs= (int*)(ws + o_ovfp);

    prep1_kernel<<<1201, 256, 0, stream>>>(x, W, xb, wt, ell, cur, ovf_cnt);
    prep2_kernel<<<79, 256, 0, stream>>>(epar, echild, cur, ell, ovf_cnt, ovf_pairs);
    gemm8k_kernel<<<128 * NT4, 512, 0, stream>>>(xb, wt, bias, probs16);
    segmax13_kernel<<<BDIM / 8, 1024, 0, stream>>>(probs16, cur, ell,
                                                   ovf_cnt, ovf_pairs, out);
}